// Round 11
// baseline (160.343 us; speedup 1.0000x reference)
//
#include <hip/hip_runtime.h>
#include <hip/hip_bf16.h>

typedef unsigned short ushort_t;
typedef __attribute__((ext_vector_type(8))) short short8;
typedef __attribute__((ext_vector_type(4))) float f32x4;

// Problem constants (B=8, L=1025, E=384, H=6, D=64, WIN=33, PAD=16)
constexpr int Bc = 8;
constexpr int Lc = 1025;
constexpr int Ec = 384;
constexpr int Hc = 6;
constexpr int Dc = 64;
constexpr int MT = Bc * Lc;              // 8200 rows
constexpr int BHLD = Bc * Hc * Lc * Dc;  // 3,148,800 elems per tensor
constexpr float SCALE = 0.125f;          // 1/sqrt(64)
constexpr int NCH = 5;                   // cls split-K chunks of 256 keys

__device__ __forceinline__ float bf2f(ushort_t u) {
    union { unsigned int u; float f; } v; v.u = ((unsigned int)u) << 16; return v.f;
}
__device__ __forceinline__ ushort_t f2bf(float f) {
    union { float f; unsigned int u; } v; v.f = f;
    unsigned int r = v.u + 0x7FFFu + ((v.u >> 16) & 1u);
    return (ushort_t)(r >> 16);
}

#define GLOAD_LDS16(gp, lp)                                                          \
    __builtin_amdgcn_global_load_lds(                                                \
        (const __attribute__((address_space(1))) unsigned int*)(gp),                 \
        (__attribute__((address_space(3))) unsigned int*)(lp), 16, 0, 0)

// ---------------------------------------------------------------------------
// Kernel 0: merged prep.  Blocks [0, 3075): cast x fp32->bf16 (float4/thread).
// Blocks [3075, 3651): transpose+cast the 4 weight matrices.
// ---------------------------------------------------------------------------
__global__ __launch_bounds__(256) void prep_kernel(
    const float* __restrict__ x, ushort_t* __restrict__ xb,
    const float* __restrict__ Wq, const float* __restrict__ Wk,
    const float* __restrict__ Wv, const float* __restrict__ Wo,
    ushort_t* __restrict__ Wt_all)
{
    const int bid = blockIdx.x;
    if (bid < 3075) {
        int i = bid * 256 + threadIdx.x;
        float4 v = ((const float4*)x)[i];
        ushort4 o;
        o.x = f2bf(v.x); o.y = f2bf(v.y); o.z = f2bf(v.z); o.w = f2bf(v.w);
        ((ushort4*)xb)[i] = o;
        return;
    }
    __shared__ float t[32][33];
    const int b2 = bid - 3075;
    const int z = b2 / 144, rem = b2 - z * 144;
    const int yy = rem / 12, xx = rem - yy * 12;
    const float* W = (z == 0) ? Wq : (z == 1) ? Wk : (z == 2) ? Wv : Wo;
    ushort_t* Wt = Wt_all + (size_t)z * Ec * Ec;
    const int x0 = xx * 32, y0 = yy * 32;
    const int tx = threadIdx.x & 31, ty = threadIdx.x >> 5;
#pragma unroll
    for (int j = 0; j < 4; j++)
        t[ty + 8 * j][tx] = W[(size_t)(y0 + ty + 8 * j) * Ec + x0 + tx];
    __syncthreads();
#pragma unroll
    for (int j = 0; j < 4; j++)
        Wt[(size_t)(x0 + ty + 8 * j) * Ec + y0 + tx] = f2bf(t[tx][ty + 8 * j]);
}

// ---------------------------------------------------------------------------
// Kernel 1: QKV projection, A-RESIDENT structure.
// Block = 64 m-rows x all 384 cols of ONE weight matrix (which = blockIdx.y).
// A strip xb[m0:m0+64, 0:384] staged to LDS ONCE (48 KB, 12 gloads/wave);
// then 18 B-stages (3 n-subtiles x 6 K-steps) with 2-deep counted-vmcnt
// pipeline (4 gloads/wave/stage, vmcnt(4) steady).  B is L2-resident W.
// 4 waves: wr=wid&1 (32-row half), wc=wid>>1 (64-col half); acc 2x4 per
// subtile, epilogue + acc reset at kt==5.  LDS 48+2*16=80 KB -> 2 blocks/CU.
// ---------------------------------------------------------------------------
__global__ __launch_bounds__(256) void qkv_mfma_kernel(
    const ushort_t* __restrict__ xb, const ushort_t* __restrict__ Wt,
    const float* __restrict__ bq, const float* __restrict__ bk,
    const float* __restrict__ bv, ushort_t* __restrict__ qkv)
{
    __shared__ __align__(16) ushort_t Asm[64 * 384];      // [row][48 chunks] swz
    __shared__ __align__(16) ushort_t Bsm[2][128 * 64];

    const int tid = threadIdx.x;
    const int lane = tid & 63;
    const int wid = tid >> 6;
    const int wr = wid & 1, wc = wid >> 1;
    const int m0 = blockIdx.x * 64;
    const int which = blockIdx.y;
    const ushort_t* Wmat = Wt + (size_t)which * Ec * Ec;
    const float* bias = (which == 0) ? bq : (which == 1) ? bk : bv;
    ushort_t* outp = qkv + (size_t)which * BHLD;

    // ---- stage A once: 64 rows x 48 chunks = 3072 chunks, 12 per wave ----
#pragma unroll
    for (int i = 0; i < 12; i++) {
        int wchunk = wid * 12 + i;                 // 0..47
        int ci = wchunk * 64 + lane;               // 0..3071
        int row = ci / 48, c = ci - row * 48;
        int cg = (c & ~7) | ((c & 7) ^ (row & 7)); // inverse swizzle on source
        int rowA = m0 + row; rowA = rowA < MT ? rowA : MT - 1;
        GLOAD_LDS16(xb + (size_t)rowA * Ec + cg * 8,
                    Asm + (size_t)wchunk * 512);
    }

    // B stage for flat step S (ns = S/6, kt = S%6) into buffer BUF
#define B_STAGE(S, BUF)                                                          \
    {                                                                            \
        int ns_ = (S) / 6, kt_ = (S) - ns_ * 6;                                  \
        _Pragma("unroll")                                                        \
        for (int c = 0; c < 4; c++) {                                            \
            int ci  = (wid * 4 + c) * 64 + lane;                                 \
            int row = ci >> 3, kc = ci & 7;                                      \
            int kcs = kc ^ (row & 7);                                            \
            GLOAD_LDS16(Wmat + (size_t)(ns_ * 128 + row) * Ec + kt_ * 64 + kcs * 8, \
                        Bsm[BUF] + (size_t)(wid * 4 + c) * 512);                 \
        }                                                                        \
    }

    B_STAGE(0, 0);
    B_STAGE(1, 1);
    // outstanding/wave: A(12) + B0(4) + B1(4) = 20

    f32x4 acc[2][4];
#pragma unroll
    for (int i = 0; i < 2; i++)
#pragma unroll
        for (int j = 0; j < 4; j++) acc[i][j] = (f32x4){0.f, 0.f, 0.f, 0.f};

    const int colL = lane & 15;
    const int rowL = (lane >> 4) * 4;

    for (int s = 0; s < 18; ++s) {
        const int cb = s & 1;
        const int ns = s / 6, kt = s - ns * 6;
        if (s < 17) { asm volatile("s_waitcnt vmcnt(4)" ::: "memory"); }
        else        { asm volatile("s_waitcnt vmcnt(0)" ::: "memory"); }
        __builtin_amdgcn_sched_barrier(0);
        __builtin_amdgcn_s_barrier();            // A + B(s) staged (all waves)

        short8 a[2][2], b[2][4];
#pragma unroll
        for (int ki = 0; ki < 2; ki++) {
            const int kc = ki * 4 + (lane >> 4);
#pragma unroll
            for (int mi = 0; mi < 2; mi++) {
                int row = wr * 32 + mi * 16 + (lane & 15);
                a[ki][mi] = *(const short8*)(
                    Asm + row * 384 + (kt * 8 + (kc ^ (row & 7))) * 8);
            }
#pragma unroll
            for (int ni = 0; ni < 4; ni++) {
                int row = wc * 64 + ni * 16 + (lane & 15);
                b[ki][ni] = *(const short8*)(
                    Bsm[cb] + row * 64 + ((kc ^ (row & 7)) * 8));
            }
        }
        asm volatile("s_waitcnt lgkmcnt(0)" ::: "memory");
        __builtin_amdgcn_sched_barrier(0);
        __builtin_amdgcn_s_barrier();            // all waves done reading cb

        if (s + 2 < 18) B_STAGE(s + 2, cb);      // refill freed buffer

#pragma unroll
        for (int ki = 0; ki < 2; ki++)
#pragma unroll
            for (int mi = 0; mi < 2; mi++)
#pragma unroll
                for (int ni = 0; ni < 4; ni++)
                    acc[mi][ni] = __builtin_amdgcn_mfma_f32_16x16x32_bf16(
                        a[ki][mi], b[ki][ni], acc[mi][ni], 0, 0, 0);

        if (kt == 5) {
            // ---- epilogue for subtile ns, then reset acc ----
#pragma unroll
            for (int ni = 0; ni < 4; ni++) {
                int nm = ns * 128 + wc * 64 + ni * 16 + colL;   // 0..383
                float bv_ = bias[nm];
                int h = nm >> 6, d = nm & 63;
#pragma unroll
                for (int mi = 0; mi < 2; mi++) {
#pragma unroll
                    for (int r = 0; r < 4; r++) {
                        int m = m0 + wr * 32 + mi * 16 + rowL + r;
                        if (m < MT) {
                            int b_ = m / Lc, l = m - b_ * Lc;
                            outp[((size_t)(b_ * Hc + h) * Lc + l) * Dc + d] =
                                f2bf(acc[mi][ni][r] + bv_);
                        }
                    }
                    acc[mi][ni] = (f32x4){0.f, 0.f, 0.f, 0.f};
                }
            }
        }
    }
#undef B_STAGE
}

// ---------------------------------------------------------------------------
// Kernel 2: CLS split-K partials. grid (48, NCH).
// ---------------------------------------------------------------------------
__global__ __launch_bounds__(256) void cls_part_kernel(
    const ushort_t* __restrict__ qkv, float* __restrict__ part)
{
    const int bh = blockIdx.x, ch = blockIdx.y;
    const int base = ch * 256;
    const int count = min(256, Lc - base);
    const ushort_t* Q = qkv + (size_t)bh * Lc * Dc;
    const ushort_t* K = Q + (size_t)BHLD;
    const ushort_t* V = Q + 2 * (size_t)BHLD;

    __shared__ float qs[64];
    __shared__ float ps[256];
    __shared__ float red[256];

    const int tid = threadIdx.x;
    if (tid < 64) qs[tid] = bf2f(Q[tid]);
    __syncthreads();

    float s = -1e30f;
    if (tid < count) {
        const ushort4* kp = (const ushort4*)(K + (size_t)(base + tid) * Dc);
        float acc = 0.f;
#pragma unroll
        for (int c = 0; c < 16; c++) {
            ushort4 kv = kp[c];
            acc += qs[c * 4 + 0] * bf2f(kv.x) + qs[c * 4 + 1] * bf2f(kv.y) +
                   qs[c * 4 + 2] * bf2f(kv.z) + qs[c * 4 + 3] * bf2f(kv.w);
        }
        s = acc * SCALE;
    }
    red[tid] = s; __syncthreads();
    for (int off = 128; off > 0; off >>= 1) {
        if (tid < off) red[tid] = fmaxf(red[tid], red[tid + off]);
        __syncthreads();
    }
    const float m = red[0];
    __syncthreads();

    float p = (tid < count) ? __expf(s - m) : 0.f;
    ps[tid] = p;
    red[tid] = p; __syncthreads();
    for (int off = 128; off > 0; off >>= 1) {
        if (tid < off) red[tid] += red[tid + off];
        __syncthreads();
    }
    const float S = red[0];
    __syncthreads();

    const int d = tid & 63, sl = tid >> 6;
    float acc = 0.f;
    for (int i = sl; i < count; i += 4)
        acc += ps[i] * bf2f(V[(size_t)(base + i) * Dc + d]);
    red[tid] = acc; __syncthreads();
    if (tid < 64) {
        float o = red[tid] + red[tid + 64] + red[tid + 128] + red[tid + 192];
        float* pp = part + (size_t)(bh * NCH + ch) * 66;
        pp[2 + tid] = o;
        if (tid == 0) { pp[0] = m; pp[1] = S; }
    }
}

// ---------------------------------------------------------------------------
// Kernel 3: windowed MFMA attention (NT=7 j-tiles, in-kernel V transpose)
//           + CLS combine.  grid (17, 48), 256 threads (4 waves).
// ---------------------------------------------------------------------------
__global__ __launch_bounds__(256) void win_attn_kernel(
    const ushort_t* __restrict__ qkv, const float* __restrict__ part,
    ushort_t* __restrict__ attnb)
{
    __shared__ __align__(16) ushort_t Kb[128 * 64];   // K rows 0..111 used
    __shared__ __align__(16) ushort_t Vb[64 * 128];   // V^T, chunk-xor (d&15)
    __shared__ __align__(16) ushort_t QP[64 * 128];   // Q (8KB) then P (16KB)

    const int bh = blockIdx.y;
    const int tid = threadIdx.x, lane = tid & 63, wid = tid >> 6;
    const int b_ = bh / Hc, h = bh - b_ * Hc;

    if (blockIdx.x == 16) {
        // -------- CLS combine --------
        if (tid >= 64) return;
        float M = -1e30f;
#pragma unroll
        for (int ch = 0; ch < NCH; ch++)
            M = fmaxf(M, part[(size_t)(bh * NCH + ch) * 66]);
        float S = 0.f, O = 0.f;
#pragma unroll
        for (int ch = 0; ch < NCH; ch++) {
            const float* pp = part + (size_t)(bh * NCH + ch) * 66;
            float w = __expf(pp[0] - M);
            S += pp[1] * w;
            O += pp[2 + tid] * w;
        }
        attnb[(size_t)(b_ * Lc) * Ec + h * 64 + tid] = f2bf(O / S);
        return;
    }

    // -------- windowed branch --------
    const int t = blockIdx.x;
    const int l0 = 1 + t * 64;
    const int k0n = l0 - 16;            // slot j -> kpos k0n + j (j <= 95)
    const ushort_t* Qg = qkv + (size_t)bh * Lc * Dc;
    const ushort_t* Kg = Qg + (size_t)BHLD;
    const ushort_t* Vg = Qg + 2 * (size_t)BHLD;

    // V: global -> regs (112 rows x 8 d-chunks of 16B = 896 chunks)
    short8 vreg[4];
    int vrow[4], vdc[4];
#pragma unroll
    for (int i = 0; i < 4; i++) {
        int ci = i * 256 + tid;
        if (ci < 896) {
            int j = ci >> 3, dc = ci & 7;
            int kp = (j <= 95) ? min(max(k0n + j, 0), 1024) : 0;
            vreg[i] = *(const short8*)(Vg + (size_t)kp * Dc + dc * 8);
            vrow[i] = j; vdc[i] = dc;
        } else { vrow[i] = -1; vdc[i] = 0; }
    }

    // K rows 0..111 (14 wave-chunks) + Q rows 0..63 via global_load_lds
#pragma unroll
    for (int i = 0; i < 4; i++) {
        int wchunk = i * 4 + wid;        // 0..15; K needs 0..13 (uniform/wave)
        if (wchunk < 14) {
            int p = wchunk * 64 + lane;
            int j = p >> 3, c = p & 7, g = c ^ (j & 7);
            int kp = (j <= 95) ? min(max(k0n + j, 0), 1024) : 0;
            GLOAD_LDS16(Kg + (size_t)kp * Dc + g * 8,
                        Kb + (size_t)wchunk * 512);
        }
    }
#pragma unroll
    for (int i = 0; i < 2; i++) {
        int p = (i * 4 + wid) * 64 + lane;
        int q = p >> 3, c = p & 7, g = c ^ (q & 7);
        GLOAD_LDS16(Qg + (size_t)(l0 + q) * Dc + g * 8,
                    QP + (size_t)(i * 4 + wid) * 512);
    }

    // V: regs -> transposed LDS (Vb[d][j], chunk-xor (d&15))
#pragma unroll
    for (int i = 0; i < 4; i++) {
        if (vrow[i] >= 0) {
            int j = vrow[i], jc3 = j >> 3, j7 = j & 7;
#pragma unroll
            for (int z = 0; z < 8; z++) {
                int d = vdc[i] * 8 + z;
                Vb[d * 128 + ((jc3 ^ (d & 15)) * 8) + j7] = (ushort_t)vreg[i][z];
            }
        }
    }
    // zero logical chunks 14,15 of every Vb row (slots 112..127)
    if (tid < 128) {
        int d = tid >> 1, lcn = 14 + (tid & 1);
        *(short8*)(Vb + d * 128 + ((lcn ^ (d & 15)) * 8)) =
            (short8){0, 0, 0, 0, 0, 0, 0, 0};
    }
    __syncthreads();

    // ---- QK^T: wave owns q-tile wid (16 rows) x 7 j-tiles ----
    f32x4 sacc[7];
#pragma unroll
    for (int tj = 0; tj < 7; tj++) sacc[tj] = (f32x4){0.f, 0.f, 0.f, 0.f};
#pragma unroll
    for (int ki = 0; ki < 2; ki++) {
        const int gc = ki * 4 + (lane >> 4);
        const int qrow = wid * 16 + (lane & 15);
        short8 a = *(const short8*)(QP + qrow * 64 + ((gc ^ (qrow & 7)) * 8));
#pragma unroll
        for (int tj = 0; tj < 7; tj++) {
            int jrow = tj * 16 + (lane & 15);
            short8 b = *(const short8*)(Kb + jrow * 64 + ((gc ^ (jrow & 7)) * 8));
            sacc[tj] = __builtin_amdgcn_mfma_f32_16x16x32_bf16(a, b, sacc[tj], 0, 0, 0);
        }
    }
    __syncthreads();   // Q region dead; P may overwrite it

    // ---- softmax (rows q = wid*16 + (lane>>4)*4 + r), write P to LDS ----
    const int qb = wid * 16 + (lane >> 4) * 4;
    const int cl = lane & 15;
    float inv[4];
#pragma unroll
    for (int r = 0; r < 4; r++) {
        const int q = qb + r;
        float sv[7];
        float mx = -1e30f;
#pragma unroll
        for (int tj = 0; tj < 7; tj++) {
            int j = tj * 16 + cl;
            int kp = k0n + j;
            bool valid = (j == 96) ||
                         ((j >= q) && (j <= q + 32) && (kp >= 1) && (kp <= 1024));
            float s = valid ? sacc[tj][r] * SCALE : -1e30f;
            sv[tj] = s;
            mx = fmaxf(mx, s);
        }
        mx = fmaxf(mx, __shfl_xor(mx, 1));
        mx = fmaxf(mx, __shfl_xor(mx, 2));
        mx = fmaxf(mx, __shfl_xor(mx, 4));
        mx = fmaxf(mx, __shfl_xor(mx, 8));
        float sum = 0.f;
#pragma unroll
        for (int tj = 0; tj < 7; tj++) {
            float pv = __expf(sv[tj] - mx);
            sv[tj] = pv;
            sum += pv;
        }
        sum += __shfl_xor(sum, 1);
        sum += __shfl_xor(sum, 2);
        sum += __shfl_xor(sum, 4);
        sum += __shfl_xor(sum, 8);
        inv[r] = 1.f / sum;
#pragma unroll
        for (int tj = 0; tj < 7; tj++) {
            int j = tj * 16 + cl;
            QP[q * 128 + (((j >> 3) ^ (q & 15)) * 8) + (j & 7)] = f2bf(sv[tj]);
        }
    }
    // zero P logical chunks 14,15 (slots 112..127) for this thread's rows
    if (cl == 0) {
#pragma unroll
        for (int r = 0; r < 4; r++) {
            int q = qb + r;
            *(short8*)(QP + q * 128 + ((14 ^ (q & 15)) * 8)) =
                (short8){0, 0, 0, 0, 0, 0, 0, 0};
            *(short8*)(QP + q * 128 + ((15 ^ (q & 15)) * 8)) =
                (short8){0, 0, 0, 0, 0, 0, 0, 0};
        }
    }
    __syncthreads();

    // ---- PV: O(16x64) per wave = 4 k-steps x 4 d-tiles ----
    f32x4 oacc[4];
#pragma unroll
    for (int dt = 0; dt < 4; dt++) oacc[dt] = (f32x4){0.f, 0.f, 0.f, 0.f};
#pragma unroll
    for (int kc = 0; kc < 4; kc++) {
        const int gc = kc * 4 + (lane >> 4);
        const int qrow = wid * 16 + (lane & 15);
        short8 pa = *(const short8*)(QP + qrow * 128 + ((gc ^ (qrow & 15)) * 8));
#pragma unroll
        for (int dt = 0; dt < 4; dt++) {
            int drow = dt * 16 + (lane & 15);
            short8 vb = *(const short8*)(Vb + drow * 128 + ((gc ^ (drow & 15)) * 8));
            oacc[dt] = __builtin_amdgcn_mfma_f32_16x16x32_bf16(pa, vb, oacc[dt], 0, 0, 0);
        }
    }

    // ---- epilogue ----
#pragma unroll
    for (int dt = 0; dt < 4; dt++) {
        int d = dt * 16 + cl;
#pragma unroll
        for (int r = 0; r < 4; r++) {
            int l = l0 + qb + r;
            attnb[(size_t)(b_ * Lc + l) * Ec + h * 64 + d] = f2bf(oacc[dt][r] * inv[r]);
        }
    }
}

// ---------------------------------------------------------------------------
// Kernel 4: output projection via bf16 MFMA, 64x128 tile (grid 129 x 3).
// 2-phase counted-vmcnt pipeline (6 gload_lds per wave per stage).
// ---------------------------------------------------------------------------
__global__ __launch_bounds__(256) void out_mfma_kernel(
    const ushort_t* __restrict__ attn_rows, const ushort_t* __restrict__ Wot,
    const float* __restrict__ bo, float* __restrict__ out)
{
    __shared__ __align__(16) ushort_t As[2][64 * 64];
    __shared__ __align__(16) ushort_t Bs[2][128 * 64];

    const int tid = threadIdx.x;
    const int lane = tid & 63;
    const int wid = tid >> 6;
    const int wr = wid & 1, wc = wid >> 1;
    const int m0 = blockIdx.x * 64;
    const int n0 = blockIdx.y * 128;

    f32x4 acc[2][4];
#pragma unroll
    for (int i = 0; i < 2; i++)
#pragma unroll
        for (int j = 0; j < 4; j++) acc[i][j] = (f32x4){0.f, 0.f, 0.f, 0.f};

#define OUT_STAGE(KT, BUF)                                                       \
    {                                                                            \
        _Pragma("unroll")                                                        \
        for (int c = 0; c < 2; c++) {                                            \
            int ci  = (wid * 2 + c) * 64 + lane;                                 \
            int row = ci >> 3, kc = ci & 7;                                      \
            int kcs = kc ^ (row & 7);                                            \
            int rowA = m0 + row; rowA = rowA < MT ? rowA : MT - 1;               \
            GLOAD_LDS16(attn_rows + (size_t)rowA * Ec + (KT) + kcs * 8,          \
                        As[BUF] + (size_t)(wid * 2 + c) * 512);                  \
        }                                                                        \
        _Pragma("unroll")                                                        \
        for (int c = 0; c < 4; c++) {                                            \
            int ci  = (wid * 4 + c) * 64 + lane;                                 \
            int row = ci >> 3, kc = ci & 7;                                      \
            int kcs = kc ^ (row & 7);                                            \
            GLOAD_LDS16(Wot + (size_t)(n0 + row) * Ec + (KT) + kcs * 8,          \
                        Bs[BUF] + (size_t)(wid * 4 + c) * 512);                  \
        }                                                                        \
    }

    OUT_STAGE(0, 0);
    OUT_STAGE(64, 1);

    for (int t = 0; t < 6; ++t) {
        const int cb = t & 1;
        if (t < 5) { asm volatile("s_waitcnt vmcnt(6)" ::: "memory"); }
        else       { asm volatile("s_waitcnt vmcnt(0)" ::: "memory"); }
        __builtin_amdgcn_sched_barrier(0);
        __builtin_amdgcn_s_barrier();

        short8 a[2][2], b[2][4];
#pragma unroll
        for (int ki = 0; ki < 2; ki++) {
            const int kchunk = ki * 4 + (lane >> 4);
#pragma unroll
            for (int mi = 0; mi < 2; mi++) {
                int row = wr * 32 + mi * 16 + (lane & 15);
                a[ki][mi] = *(const short8*)(As[cb] + row * 64 + ((kchunk ^ (row & 7)) * 8));
            }
#pragma unroll
            for (int ni = 0; ni < 4; ni++) {
                int row = wc * 64 + ni * 16 + (lane & 15);
                b[ki][ni] = *(const short8*)(Bs[cb] + row * 64 + ((kchunk ^ (row & 7)) * 8));
            }
        }
        asm volatile("s_waitcnt lgkmcnt(0)" ::: "memory");
        __builtin_amdgcn_sched_barrier(0);
        __builtin_amdgcn_s_barrier();

        if (t + 2 < 6) OUT_STAGE((t + 2) * 64, cb);

#pragma unroll
        for (int ki = 0; ki < 2; ki++)
#pragma unroll
            for (int mi = 0; mi < 2; mi++)
#pragma unroll
                for (int ni = 0; ni < 4; ni++)
                    acc[mi][ni] = __builtin_amdgcn_mfma_f32_16x16x32_bf16(
                        a[ki][mi], b[ki][ni], acc[mi][ni], 0, 0, 0);
    }
#undef OUT_STAGE

    const int colL = lane & 15;
    const int rowL = (lane >> 4) * 4;
#pragma unroll
    for (int ni = 0; ni < 4; ni++) {
        int n = n0 + wc * 64 + ni * 16 + colL;
        float bo_v = bo[n];
#pragma unroll
        for (int mi = 0; mi < 2; mi++) {
#pragma unroll
            for (int r = 0; r < 4; r++) {
                int m = m0 + wr * 32 + mi * 16 + rowL + r;
                if (m < MT) out[(size_t)m * Ec + n] = acc[mi][ni][r] + bo_v;
            }
        }
    }
}

// ---------------------------------------------------------------------------
extern "C" void kernel_launch(void* const* d_in, const int* in_sizes, int n_in,
                              void* d_out, int out_size, void* d_ws, size_t ws_size,
                              hipStream_t stream)
{
    const float* x  = (const float*)d_in[0];
    const float* Wq = (const float*)d_in[1];
    const float* bq = (const float*)d_in[2];
    const float* Wk = (const float*)d_in[3];
    const float* bk = (const float*)d_in[4];
    const float* Wv = (const float*)d_in[5];
    const float* bv = (const float*)d_in[6];
    const float* Wo = (const float*)d_in[7];
    const float* bo = (const float*)d_in[8];
    float* out = (float*)d_out;

    // ws layout (ushort units, all 16B-aligned):
    // xb | Wt(4) | qkv(3) | attnb | clsp(float)  ~= 26 MB
    ushort_t* xb    = (ushort_t*)d_ws;
    ushort_t* Wt    = xb + (size_t)MT * Ec;                  // 3,148,800
    ushort_t* qkvb  = Wt + (size_t)4 * Ec * Ec;              // + 589,824
    ushort_t* attnb = qkvb + (size_t)3 * BHLD;               // + 9,446,400
    float* clsp     = (float*)(attnb + (size_t)MT * Ec);     // + 3,148,800

    prep_kernel<<<3075 + 576, 256, 0, stream>>>(x, xb, Wq, Wk, Wv, Wo, Wt);

    qkv_mfma_kernel<<<dim3((MT + 63) / 64, 3), 256, 0, stream>>>(
        xb, Wt, bq, bk, bv, qkvb);

    cls_part_kernel<<<dim3(Bc * Hc, NCH), 256, 0, stream>>>(qkvb, clsp);

    win_attn_kernel<<<dim3(17, Bc * Hc), 256, 0, stream>>>(qkvb, clsp, attnb);

    out_mfma_kernel<<<dim3((MT + 63) / 64, 3), 256, 0, stream>>>(
        attnb, Wt + (size_t)3 * Ec * Ec, bo, out);
}